// Round 1
// baseline (215.353 us; speedup 1.0000x reference)
//
#include <hip/hip_runtime.h>
#include <hip/hip_bf16.h>

#define B_ 2
#define T_ 2048
#define C_ 1024
#define NH 16
#define NKV 4
#define HD 64
#define NQKV 1536

typedef __attribute__((ext_vector_type(4))) float f32x4;
typedef __attribute__((ext_vector_type(8))) short bf16x8;
typedef __attribute__((ext_vector_type(4))) short bf16x4;

__device__ __forceinline__ unsigned short f2bf(float f) {
  unsigned u = __float_as_uint(f);
  u = (u + 0x7fffu + ((u >> 16) & 1u)) >> 16;
  return (unsigned short)u;
}

// ---------------- f32 -> bf16 convert (vectorized, grid-stride) ----------------
__global__ __launch_bounds__(256) void conv_bf16(const float* __restrict__ src,
                                                 unsigned short* __restrict__ dst, int n4) {
  int i = blockIdx.x * blockDim.x + threadIdx.x;
  const int stride = gridDim.x * blockDim.x;
  for (; i < n4; i += stride) {
    const float4 v = reinterpret_cast<const float4*>(src)[i];
    ushort4 o;
    o.x = f2bf(v.x); o.y = f2bf(v.y); o.z = f2bf(v.z); o.w = f2bf(v.w);
    reinterpret_cast<ushort4*>(dst)[i] = o;
  }
}

// ---------------- GEMM: C[M,N] = A[M,K] * B[N,K]^T  (bf16 in, f32 out) ----------------
#define BM 128
#define BN 128
#define BK 32

__global__ __launch_bounds__(256) void gemm_bt(const unsigned short* __restrict__ A,
                                               const unsigned short* __restrict__ Bw,
                                               float* __restrict__ C, int M, int N, int K) {
  __shared__ unsigned short Al[BM * BK];
  __shared__ unsigned short Bl[BN * BK];
  const int tid = threadIdx.x;
  const int lane = tid & 63;
  const int wid = tid >> 6;
  const int r = lane & 15, g = lane >> 4;
  const int wm = (wid >> 1) * 64, wn = (wid & 1) * 64;
  const int bm0 = blockIdx.y * BM, bn0 = blockIdx.x * BN;
  const int srow = tid >> 2;          // 0..63
  const int scol = (tid & 3) * 8;     // 0,8,16,24
  f32x4 acc[4][4] = {};
  const size_t abase = (size_t)(bm0 + srow) * K + scol;
  const size_t bbase = (size_t)(bn0 + srow) * K + scol;
  for (int k0 = 0; k0 < K; k0 += BK) {
    bf16x8 a0 = *reinterpret_cast<const bf16x8*>(A + abase + k0);
    bf16x8 a1 = *reinterpret_cast<const bf16x8*>(A + abase + (size_t)64 * K + k0);
    bf16x8 b0 = *reinterpret_cast<const bf16x8*>(Bw + bbase + k0);
    bf16x8 b1 = *reinterpret_cast<const bf16x8*>(Bw + bbase + (size_t)64 * K + k0);
    __syncthreads();
    *reinterpret_cast<bf16x8*>(Al + srow * BK + scol) = a0;
    *reinterpret_cast<bf16x8*>(Al + (64 + srow) * BK + scol) = a1;
    *reinterpret_cast<bf16x8*>(Bl + srow * BK + scol) = b0;
    *reinterpret_cast<bf16x8*>(Bl + (64 + srow) * BK + scol) = b1;
    __syncthreads();
    bf16x8 af[4], bfr[4];
#pragma unroll
    for (int mi = 0; mi < 4; ++mi)
      af[mi] = *reinterpret_cast<const bf16x8*>(Al + (wm + mi * 16 + r) * BK + g * 8);
#pragma unroll
    for (int ni = 0; ni < 4; ++ni)
      bfr[ni] = *reinterpret_cast<const bf16x8*>(Bl + (wn + ni * 16 + r) * BK + g * 8);
#pragma unroll
    for (int mi = 0; mi < 4; ++mi)
#pragma unroll
      for (int ni = 0; ni < 4; ++ni)
        acc[mi][ni] = __builtin_amdgcn_mfma_f32_16x16x32_bf16(af[mi], bfr[ni], acc[mi][ni], 0, 0, 0);
  }
#pragma unroll
  for (int mi = 0; mi < 4; ++mi)
#pragma unroll
    for (int ni = 0; ni < 4; ++ni) {
      const int row = bm0 + wm + mi * 16 + g * 4;
      const int col = bn0 + wn + ni * 16 + r;
#pragma unroll
      for (int e = 0; e < 4; ++e)
        C[(size_t)(row + e) * N + col] = acc[mi][ni][e];
    }
}

// ---------------- postprocess: rotary + rmsnorm on q,k ; gate+ve on v ----------------
// writes Qn [B][NH][T][64] (x 1.2*0.125), Kn [B][NKV][T][64] (x 1.2), Vt [B][NKV][64][T]
__global__ __launch_bounds__(256) void postproc(
    const float* __restrict__ qkv, const float* __restrict__ x, const float* __restrict__ ve,
    const float* __restrict__ cosb, const float* __restrict__ sinb, const float* __restrict__ Wg,
    unsigned short* __restrict__ Qn, unsigned short* __restrict__ Kn, unsigned short* __restrict__ Vt) {
  const int tok = blockIdx.x;
  const int b = tok / T_, t = tok % T_;
  const int wid = threadIdx.x >> 6, lane = threadIdx.x & 63;
  const float* qrow = qkv + (size_t)tok * NQKV;
  const float c = cosb[t * 32 + (lane & 31)];
  const float s = sinb[t * 32 + (lane & 31)];
  for (int u = wid; u < 24; u += 4) {
    if (u < 20) {
      const int off = (u < 16) ? u * 64 : 1024 + (u - 16) * 64;
      float v0 = qrow[off + lane];
      float p = __shfl_xor(v0, 32);
      // lane<32: x1=v0, x2=p -> x1*c + x2*s ; lane>=32: x1=p, x2=v0 -> -x1*s + x2*c
      float rot = (lane < 32) ? (v0 * c + p * s) : (v0 * c - p * s);
      float sq = rot * rot;
#pragma unroll
      for (int m = 1; m < 64; m <<= 1) sq += __shfl_xor(sq, m);
      float outv = rot * rsqrtf(sq * (1.0f / 64.0f) + 1.1920929e-7f) * ((u < 16) ? 0.15f : 1.2f);
      if (u < 16)
        Qn[((size_t)(b * NH + u) * T_ + t) * HD + lane] = f2bf(outv);
      else
        Kn[((size_t)(b * NKV + (u - 16)) * T_ + t) * HD + lane] = f2bf(outv);
    } else {
      const int kv = u - 20;
      float dot = 0.f;
#pragma unroll
      for (int i = 0; i < 12; ++i) dot += x[(size_t)tok * C_ + i] * Wg[kv * 12 + i];
      const float gate = 3.0f / (1.0f + __expf(-dot));
      const float vv = qrow[1280 + kv * 64 + lane] + gate * ve[(size_t)tok * (NKV * HD) + kv * 64 + lane];
      Vt[((size_t)(b * NKV + kv) * HD + lane) * T_ + t] = f2bf(vv);
    }
  }
}

// ---------------- flash attention, sliding window, GQA ----------------
// grid (T/64, NH, B), 256 thr. wave w owns queries [q0+16w, q0+16w+16).
// Computes S^T = K*Q^T via mfma(A=K, B=Q); O^T += Vt * P^T via mfma(A=Vt, B=P^T).
__global__ __launch_bounds__(256) void attn_fwd(
    const unsigned short* __restrict__ Qn, const unsigned short* __restrict__ Kn,
    const unsigned short* __restrict__ Vt, unsigned short* __restrict__ Y,
    const int* __restrict__ wlp) {
  __shared__ unsigned short Pl[4][16 * 32];
  const int b = blockIdx.z, h = blockIdx.y;
  const int kvh = h >> 2;
  const int wid = threadIdx.x >> 6, lane = threadIdx.x & 63;
  const int qs = blockIdx.x * 64 + wid * 16;
  const int r = lane & 15, g = lane >> 4;
  const int wl = *wlp;
  const unsigned short* Qb = Qn + ((size_t)(b * NH + h) * T_ + qs) * HD;
  const unsigned short* Kb = Kn + (size_t)(b * NKV + kvh) * T_ * HD;
  const unsigned short* Vb = Vt + (size_t)(b * NKV + kvh) * HD * T_;
  const bf16x8 qf0 = *reinterpret_cast<const bf16x8*>(Qb + r * HD + g * 8);
  const bf16x8 qf1 = *reinterpret_cast<const bf16x8*>(Qb + r * HD + 32 + g * 8);
  float mrun = -1e30f, lrun = 0.f;
  f32x4 o[4] = {};
  int slo = qs - wl; if (slo < 0) slo = 0;
  slo &= ~31;
  const int shi = qs + 15;
  unsigned short* Pw = Pl[wid];
  const int q = qs + r;
  for (int sb = slo; sb <= shi; sb += 32) {
    f32x4 st[2];
#pragma unroll
    for (int sub = 0; sub < 2; ++sub) {
      const unsigned short* Kr = Kb + (size_t)(sb + sub * 16 + r) * HD;
      bf16x8 kf0 = *reinterpret_cast<const bf16x8*>(Kr + g * 8);
      bf16x8 kf1 = *reinterpret_cast<const bf16x8*>(Kr + 32 + g * 8);
      f32x4 z = {};
      z = __builtin_amdgcn_mfma_f32_16x16x32_bf16(kf0, qf0, z, 0, 0, 0);
      z = __builtin_amdgcn_mfma_f32_16x16x32_bf16(kf1, qf1, z, 0, 0, 0);
      st[sub] = z;
    }
    float sv[8];
    float pm = -1e30f;
#pragma unroll
    for (int sub = 0; sub < 2; ++sub)
#pragma unroll
      for (int e = 0; e < 4; ++e) {
        const int s_ = sb + sub * 16 + g * 4 + e;
        float val = st[sub][e];
        const bool ok = (s_ <= q) && (q - s_ <= wl);
        val = ok ? val : -__builtin_inff();   // -inf: exp underflows to 0 vs finite m
        sv[sub * 4 + e] = val;
        pm = fmaxf(pm, val);
      }
    pm = fmaxf(pm, __shfl_xor(pm, 16));
    pm = fmaxf(pm, __shfl_xor(pm, 32));
    const float mnew = fmaxf(mrun, pm);       // mrun init -1e30 keeps mnew finite
    const float scl = __expf(mrun - mnew);
    float ps = 0.f;
    unsigned short pb[8];
#pragma unroll
    for (int i = 0; i < 8; ++i) {
      const float p = __expf(sv[i] - mnew);
      ps += p;
      pb[i] = f2bf(p);
    }
    ps += __shfl_xor(ps, 16);
    ps += __shfl_xor(ps, 32);
    lrun = lrun * scl + ps;
    mrun = mnew;
#pragma unroll
    for (int dt = 0; dt < 4; ++dt)
#pragma unroll
      for (int e = 0; e < 4; ++e) o[dt][e] *= scl;
    // bounce P through per-wave LDS: store P[q=r][s_local], re-read as B-fragment
    bf16x4 lo, hi;
#pragma unroll
    for (int e = 0; e < 4; ++e) { lo[e] = (short)pb[e]; hi[e] = (short)pb[4 + e]; }
    *reinterpret_cast<bf16x4*>(Pw + r * 32 + g * 4) = lo;
    *reinterpret_cast<bf16x4*>(Pw + r * 32 + 16 + g * 4) = hi;
    asm volatile("s_waitcnt lgkmcnt(0)" ::: "memory");
    const bf16x8 pf = *reinterpret_cast<const bf16x8*>(Pw + r * 32 + g * 8);
#pragma unroll
    for (int dt = 0; dt < 4; ++dt) {
      const bf16x8 vf = *reinterpret_cast<const bf16x8*>(Vb + (size_t)(dt * 16 + r) * T_ + sb + g * 8);
      o[dt] = __builtin_amdgcn_mfma_f32_16x16x32_bf16(vf, pf, o[dt], 0, 0, 0);
    }
  }
  const float inv = 1.0f / lrun;
  unsigned short* Yb = Y + ((size_t)(b * T_) + qs + r) * (NH * HD) + h * HD;
#pragma unroll
  for (int dt = 0; dt < 4; ++dt)
#pragma unroll
    for (int e = 0; e < 4; ++e)
      Yb[dt * 16 + g * 4 + e] = f2bf(o[dt][e] * inv);
}

extern "C" void kernel_launch(void* const* d_in, const int* in_sizes, int n_in,
                              void* d_out, int out_size, void* d_ws, size_t ws_size,
                              hipStream_t stream) {
  const float* x    = (const float*)d_in[0];
  const float* ve   = (const float*)d_in[1];
  const float* cosb = (const float*)d_in[2];
  const float* sinb = (const float*)d_in[3];
  const float* Wq   = (const float*)d_in[4];
  const float* Wk   = (const float*)d_in[5];
  const float* Wv   = (const float*)d_in[6];
  const float* Wo   = (const float*)d_in[7];
  const float* Wg   = (const float*)d_in[8];
  const int*   wlp  = (const int*)d_in[9];

  char* ws = (char*)d_ws;
  unsigned short* xb    = (unsigned short*)ws; ws += (size_t)4096 * 1024 * 2;
  unsigned short* wqkvb = (unsigned short*)ws; ws += (size_t)1536 * 1024 * 2;
  unsigned short* wob   = (unsigned short*)ws; ws += (size_t)1024 * 1024 * 2;
  float*          qkv   = (float*)ws;          ws += (size_t)4096 * 1536 * 4;
  unsigned short* Qn    = (unsigned short*)ws; ws += (size_t)B_ * NH * T_ * HD * 2;
  unsigned short* Kn    = (unsigned short*)ws; ws += (size_t)B_ * NKV * T_ * HD * 2;
  unsigned short* Vt    = (unsigned short*)ws; ws += (size_t)B_ * NKV * HD * T_ * 2;
  unsigned short* yb    = (unsigned short*)ws; ws += (size_t)4096 * 1024 * 2;

  conv_bf16<<<dim3(1024), dim3(256), 0, stream>>>(x, xb, 4096 * 1024 / 4);
  conv_bf16<<<dim3(512), dim3(256), 0, stream>>>(Wq, wqkvb, 1024 * 1024 / 4);
  conv_bf16<<<dim3(128), dim3(256), 0, stream>>>(Wk, wqkvb + (size_t)1024 * 1024, 256 * 1024 / 4);
  conv_bf16<<<dim3(128), dim3(256), 0, stream>>>(Wv, wqkvb + (size_t)1280 * 1024, 256 * 1024 / 4);
  conv_bf16<<<dim3(512), dim3(256), 0, stream>>>(Wo, wob, 1024 * 1024 / 4);

  gemm_bt<<<dim3(NQKV / BN, 4096 / BM), dim3(256), 0, stream>>>(xb, wqkvb, qkv, 4096, NQKV, 1024);

  postproc<<<dim3(4096), dim3(256), 0, stream>>>(qkv, x, ve, cosb, sinb, Wg, Qn, Kn, Vt);

  attn_fwd<<<dim3(T_ / 64, NH, B_), dim3(256), 0, stream>>>(Qn, Kn, Vt, yb, wlp);

  gemm_bt<<<dim3(1024 / BN, 4096 / BM), dim3(256), 0, stream>>>(yb, wob, (float*)d_out, 4096, 1024, 1024);
}

// Round 2
// 202.233 us; speedup vs baseline: 1.0649x; 1.0649x over previous
//
#include <hip/hip_runtime.h>
#include <hip/hip_bf16.h>

#define B_ 2
#define T_ 2048
#define C_ 1024
#define NH 16
#define NKV 4
#define HD 64
#define NQKV 1536

typedef __attribute__((ext_vector_type(4))) float f32x4;
typedef __attribute__((ext_vector_type(8))) short bf16x8;
typedef __attribute__((ext_vector_type(4))) short bf16x4;

__device__ __forceinline__ unsigned short f2bf(float f) {
  unsigned u = __float_as_uint(f);
  u = (u + 0x7fffu + ((u >> 16) & 1u)) >> 16;
  return (unsigned short)u;
}

// ---------------- f32 -> bf16 convert (vectorized, grid-stride) ----------------
__global__ __launch_bounds__(256) void conv_bf16(const float* __restrict__ src,
                                                 unsigned short* __restrict__ dst, int n4) {
  int i = blockIdx.x * blockDim.x + threadIdx.x;
  const int stride = gridDim.x * blockDim.x;
  for (; i < n4; i += stride) {
    const float4 v = reinterpret_cast<const float4*>(src)[i];
    ushort4 o;
    o.x = f2bf(v.x); o.y = f2bf(v.y); o.z = f2bf(v.z); o.w = f2bf(v.w);
    reinterpret_cast<ushort4*>(dst)[i] = o;
  }
}

// ---------------- GEMM: C[M,N] = A[M,K] * B[N,K]^T  (bf16 in, f32 out) ----------------
#define BM 128
#define BN 128
#define BK 32

__global__ __launch_bounds__(256) void gemm_bt(const unsigned short* __restrict__ A,
                                               const unsigned short* __restrict__ Bw,
                                               float* __restrict__ C, int M, int N, int K) {
  __shared__ unsigned short Al[BM * BK];
  __shared__ unsigned short Bl[BN * BK];
  const int tid = threadIdx.x;
  const int lane = tid & 63;
  const int wid = tid >> 6;
  const int r = lane & 15, g = lane >> 4;
  const int wm = (wid >> 1) * 64, wn = (wid & 1) * 64;
  const int bm0 = blockIdx.y * BM, bn0 = blockIdx.x * BN;
  const int srow = tid >> 2;          // 0..63
  const int scol = (tid & 3) * 8;     // 0,8,16,24
  f32x4 acc[4][4] = {};
  const size_t abase = (size_t)(bm0 + srow) * K + scol;
  const size_t bbase = (size_t)(bn0 + srow) * K + scol;
  for (int k0 = 0; k0 < K; k0 += BK) {
    bf16x8 a0 = *reinterpret_cast<const bf16x8*>(A + abase + k0);
    bf16x8 a1 = *reinterpret_cast<const bf16x8*>(A + abase + (size_t)64 * K + k0);
    bf16x8 b0 = *reinterpret_cast<const bf16x8*>(Bw + bbase + k0);
    bf16x8 b1 = *reinterpret_cast<const bf16x8*>(Bw + bbase + (size_t)64 * K + k0);
    __syncthreads();
    *reinterpret_cast<bf16x8*>(Al + srow * BK + scol) = a0;
    *reinterpret_cast<bf16x8*>(Al + (64 + srow) * BK + scol) = a1;
    *reinterpret_cast<bf16x8*>(Bl + srow * BK + scol) = b0;
    *reinterpret_cast<bf16x8*>(Bl + (64 + srow) * BK + scol) = b1;
    __syncthreads();
    bf16x8 af[4], bfr[4];
#pragma unroll
    for (int mi = 0; mi < 4; ++mi)
      af[mi] = *reinterpret_cast<const bf16x8*>(Al + (wm + mi * 16 + r) * BK + g * 8);
#pragma unroll
    for (int ni = 0; ni < 4; ++ni)
      bfr[ni] = *reinterpret_cast<const bf16x8*>(Bl + (wn + ni * 16 + r) * BK + g * 8);
#pragma unroll
    for (int mi = 0; mi < 4; ++mi)
#pragma unroll
      for (int ni = 0; ni < 4; ++ni)
        acc[mi][ni] = __builtin_amdgcn_mfma_f32_16x16x32_bf16(af[mi], bfr[ni], acc[mi][ni], 0, 0, 0);
  }
#pragma unroll
  for (int mi = 0; mi < 4; ++mi)
#pragma unroll
    for (int ni = 0; ni < 4; ++ni) {
      const int row = bm0 + wm + mi * 16 + g * 4;
      const int col = bn0 + wn + ni * 16 + r;
#pragma unroll
      for (int e = 0; e < 4; ++e)
        C[(size_t)(row + e) * N + col] = acc[mi][ni][e];
    }
}

// ---------------- postprocess: rotary + rmsnorm on q,k ; gate+ve on v ----------------
// writes Qn [B][NH][T][64] (x QK_SCALE*softmax_scale*log2e), Kn [B][NKV][T][64] (x QK_SCALE),
// Vt [B][NKV][64][T]
__global__ __launch_bounds__(256) void postproc(
    const float* __restrict__ qkv, const float* __restrict__ x, const float* __restrict__ ve,
    const float* __restrict__ cosb, const float* __restrict__ sinb, const float* __restrict__ Wg,
    unsigned short* __restrict__ Qn, unsigned short* __restrict__ Kn, unsigned short* __restrict__ Vt) {
  const int tok = blockIdx.x;
  const int b = tok / T_, t = tok % T_;
  const int wid = threadIdx.x >> 6, lane = threadIdx.x & 63;
  const float* qrow = qkv + (size_t)tok * NQKV;
  const float c = cosb[t * 32 + (lane & 31)];
  const float s = sinb[t * 32 + (lane & 31)];
  for (int u = wid; u < 24; u += 4) {
    if (u < 20) {
      const int off = (u < 16) ? u * 64 : 1024 + (u - 16) * 64;
      float v0 = qrow[off + lane];
      float p = __shfl_xor(v0, 32);
      // lane<32: x1=v0, x2=p -> x1*c + x2*s ; lane>=32: x1=p, x2=v0 -> -x1*s + x2*c
      float rot = (lane < 32) ? (v0 * c + p * s) : (v0 * c - p * s);
      float sq = rot * rot;
#pragma unroll
      for (int m = 1; m < 64; m <<= 1) sq += __shfl_xor(sq, m);
      // Q: 1.2 * (1/8 softmax scale) * log2(e) folded; K: 1.2
      float outv = rot * rsqrtf(sq * (1.0f / 64.0f) + 1.1920929e-7f) *
                   ((u < 16) ? 0.21640425613334453f : 1.2f);
      if (u < 16)
        Qn[((size_t)(b * NH + u) * T_ + t) * HD + lane] = f2bf(outv);
      else
        Kn[((size_t)(b * NKV + (u - 16)) * T_ + t) * HD + lane] = f2bf(outv);
    } else {
      const int kv = u - 20;
      float dot = 0.f;
#pragma unroll
      for (int i = 0; i < 12; ++i) dot += x[(size_t)tok * C_ + i] * Wg[kv * 12 + i];
      const float gate = 3.0f / (1.0f + __expf(-dot));
      const float vv = qrow[1280 + kv * 64 + lane] + gate * ve[(size_t)tok * (NKV * HD) + kv * 64 + lane];
      Vt[((size_t)(b * NKV + kv) * HD + lane) * T_ + t] = f2bf(vv);
    }
  }
}

// ---------------- flash attention, sliding window, GQA ----------------
// grid (32, NH, B), 256 thr. wave w owns q-strip (w*32 + blockIdx.x)*16 (quarter-interleaved
// for load balance). KVBLK=64 per softmax update. Scores arrive pre-scaled by log2(e) -> exp2.
// S^T = K*Q^T via mfma(A=K, B=Q); O^T += Vt * P^T via mfma(A=Vt, B=P^T), P bounced through
// a swizzled per-wave LDS tile [16 q][64 s] (byte ^= (r&7)<<4 kills the 64B-stride conflict).
__global__ __launch_bounds__(256) void attn_fwd(
    const unsigned short* __restrict__ Qn, const unsigned short* __restrict__ Kn,
    const unsigned short* __restrict__ Vt, unsigned short* __restrict__ Y,
    const int* __restrict__ wlp) {
  __shared__ unsigned short Pl[4][16 * 64];   // 2KB per wave
  const int b = blockIdx.z, h = blockIdx.y;
  const int kvh = h >> 2;
  const int wid = threadIdx.x >> 6, lane = threadIdx.x & 63;
  const int qs = (wid * 32 + blockIdx.x) * 16;
  const int r = lane & 15, g = lane >> 4;
  const int wl = *wlp;
  const unsigned short* Qb = Qn + ((size_t)(b * NH + h) * T_ + qs) * HD;
  const unsigned short* Kb = Kn + (size_t)(b * NKV + kvh) * T_ * HD;
  const unsigned short* Vb = Vt + (size_t)(b * NKV + kvh) * HD * T_;
  const bf16x8 qf0 = *reinterpret_cast<const bf16x8*>(Qb + r * HD + g * 8);
  const bf16x8 qf1 = *reinterpret_cast<const bf16x8*>(Qb + r * HD + 32 + g * 8);
  float mrun = -1e30f, lrun = 0.f;
  f32x4 o[4] = {};
  int slo = qs - wl; if (slo < 0) slo = 0;
  slo &= ~63;
  const int shi = qs + 15;
  char* Pwb = (char*)Pl[wid];
  const int swz = (r & 7) << 4;
  const int q = qs + r;
  for (int sb = slo; sb <= shi; sb += 64) {
    float sv[16];
#pragma unroll
    for (int sub = 0; sub < 4; ++sub) {
      const unsigned short* Kr = Kb + (size_t)(sb + sub * 16 + r) * HD;
      bf16x8 kf0 = *reinterpret_cast<const bf16x8*>(Kr + g * 8);
      bf16x8 kf1 = *reinterpret_cast<const bf16x8*>(Kr + 32 + g * 8);
      f32x4 z = {};
      z = __builtin_amdgcn_mfma_f32_16x16x32_bf16(kf0, qf0, z, 0, 0, 0);
      z = __builtin_amdgcn_mfma_f32_16x16x32_bf16(kf1, qf1, z, 0, 0, 0);
#pragma unroll
      for (int e = 0; e < 4; ++e) sv[sub * 4 + e] = z[e];
    }
    // edge blocks only: causal edge (sb+63 > qs) or window edge (sb < qs+15-wl)
    if (sb + 63 > qs || sb < shi - wl) {
#pragma unroll
      for (int i = 0; i < 16; ++i) {
        const int s_ = sb + (i >> 2) * 16 + g * 4 + (i & 3);
        const bool ok = (unsigned)(q - s_) <= (unsigned)wl;  // 0 <= q-s_ <= wl
        sv[i] = ok ? sv[i] : -__builtin_inff();
      }
    }
    float pm = sv[0];
#pragma unroll
    for (int i = 1; i < 16; ++i) pm = fmaxf(pm, sv[i]);
    pm = fmaxf(pm, __shfl_xor(pm, 16));
    pm = fmaxf(pm, __shfl_xor(pm, 32));
    if (!__all(pm <= mrun + 8.0f)) {          // defer-max (THR=8 in log2 units)
      const float mnew = fmaxf(mrun, pm);
      const float scl = exp2f(mrun - mnew);
      lrun *= scl;
#pragma unroll
      for (int dt = 0; dt < 4; ++dt)
#pragma unroll
        for (int e = 0; e < 4; ++e) o[dt][e] *= scl;
      mrun = mnew;
    }
    float ps = 0.f;
    unsigned short pb[16];
#pragma unroll
    for (int i = 0; i < 16; ++i) {
      const float p = exp2f(sv[i] - mrun);    // scores pre-scaled by log2(e)
      ps += p;
      pb[i] = f2bf(p);
    }
    ps += __shfl_xor(ps, 16);
    ps += __shfl_xor(ps, 32);
    lrun += ps;
    // store P^T tile [q=r][s 0..63] to swizzled LDS
#pragma unroll
    for (int sub = 0; sub < 4; ++sub) {
      bf16x4 w;
#pragma unroll
      for (int e = 0; e < 4; ++e) w[e] = (short)pb[sub * 4 + e];
      *reinterpret_cast<bf16x4*>(Pwb + ((r * 128 + sub * 32 + g * 8) ^ swz)) = w;
    }
    asm volatile("s_waitcnt lgkmcnt(0)" ::: "memory");
#pragma unroll
    for (int c = 0; c < 2; ++c) {
      const bf16x8 pf = *reinterpret_cast<const bf16x8*>(Pwb + ((r * 128 + c * 64 + g * 16) ^ swz));
#pragma unroll
      for (int dt = 0; dt < 4; ++dt) {
        const bf16x8 vf = *reinterpret_cast<const bf16x8*>(Vb + (size_t)(dt * 16 + r) * T_ + sb + c * 32 + g * 8);
        o[dt] = __builtin_amdgcn_mfma_f32_16x16x32_bf16(vf, pf, o[dt], 0, 0, 0);
      }
    }
  }
  const float inv = 1.0f / lrun;
  unsigned short* Yb = Y + ((size_t)(b * T_) + qs + r) * (NH * HD) + h * HD;
#pragma unroll
  for (int dt = 0; dt < 4; ++dt)
#pragma unroll
    for (int e = 0; e < 4; ++e)
      Yb[dt * 16 + g * 4 + e] = f2bf(o[dt][e] * inv);
}

extern "C" void kernel_launch(void* const* d_in, const int* in_sizes, int n_in,
                              void* d_out, int out_size, void* d_ws, size_t ws_size,
                              hipStream_t stream) {
  const float* x    = (const float*)d_in[0];
  const float* ve   = (const float*)d_in[1];
  const float* cosb = (const float*)d_in[2];
  const float* sinb = (const float*)d_in[3];
  const float* Wq   = (const float*)d_in[4];
  const float* Wk   = (const float*)d_in[5];
  const float* Wv   = (const float*)d_in[6];
  const float* Wo   = (const float*)d_in[7];
  const float* Wg   = (const float*)d_in[8];
  const int*   wlp  = (const int*)d_in[9];

  char* ws = (char*)d_ws;
  unsigned short* xb    = (unsigned short*)ws; ws += (size_t)4096 * 1024 * 2;
  unsigned short* wqkvb = (unsigned short*)ws; ws += (size_t)1536 * 1024 * 2;
  unsigned short* wob   = (unsigned short*)ws; ws += (size_t)1024 * 1024 * 2;
  float*          qkv   = (float*)ws;          ws += (size_t)4096 * 1536 * 4;
  unsigned short* Qn    = (unsigned short*)ws; ws += (size_t)B_ * NH * T_ * HD * 2;
  unsigned short* Kn    = (unsigned short*)ws; ws += (size_t)B_ * NKV * T_ * HD * 2;
  unsigned short* Vt    = (unsigned short*)ws; ws += (size_t)B_ * NKV * HD * T_ * 2;
  unsigned short* yb    = (unsigned short*)ws; ws += (size_t)4096 * 1024 * 2;

  conv_bf16<<<dim3(1024), dim3(256), 0, stream>>>(x, xb, 4096 * 1024 / 4);
  conv_bf16<<<dim3(512), dim3(256), 0, stream>>>(Wq, wqkvb, 1024 * 1024 / 4);
  conv_bf16<<<dim3(128), dim3(256), 0, stream>>>(Wk, wqkvb + (size_t)1024 * 1024, 256 * 1024 / 4);
  conv_bf16<<<dim3(128), dim3(256), 0, stream>>>(Wv, wqkvb + (size_t)1280 * 1024, 256 * 1024 / 4);
  conv_bf16<<<dim3(512), dim3(256), 0, stream>>>(Wo, wob, 1024 * 1024 / 4);

  gemm_bt<<<dim3(NQKV / BN, 4096 / BM), dim3(256), 0, stream>>>(xb, wqkvb, qkv, 4096, NQKV, 1024);

  postproc<<<dim3(4096), dim3(256), 0, stream>>>(qkv, x, ve, cosb, sinb, Wg, Qn, Kn, Vt);

  attn_fwd<<<dim3(32, NH, B_), dim3(256), 0, stream>>>(Qn, Kn, Vt, yb, wlp);

  gemm_bt<<<dim3(1024 / BN, 4096 / BM), dim3(256), 0, stream>>>(yb, wob, (float*)d_out, 4096, 1024, 1024);
}

// Round 3
// 138.362 us; speedup vs baseline: 1.5564x; 1.4616x over previous
//
#include <hip/hip_runtime.h>
#include <hip/hip_bf16.h>

#define B_ 2
#define T_ 2048
#define C_ 1024
#define NH 16
#define NKV 4
#define HD 64
#define NQKV 1536
#define KVB 64

typedef __attribute__((ext_vector_type(4))) float f32x4;
typedef __attribute__((ext_vector_type(8))) short bf16x8;
typedef __attribute__((ext_vector_type(4))) short bf16x4;

__device__ __forceinline__ unsigned short f2bf(float f) {
  unsigned u = __float_as_uint(f);
  u = (u + 0x7fffu + ((u >> 16) & 1u)) >> 16;
  return (unsigned short)u;
}

// ---------------- f32 -> bf16 convert (vectorized, grid-stride) ----------------
__global__ __launch_bounds__(256) void conv_bf16(const float* __restrict__ src,
                                                 unsigned short* __restrict__ dst, int n4) {
  int i = blockIdx.x * blockDim.x + threadIdx.x;
  const int stride = gridDim.x * blockDim.x;
  for (; i < n4; i += stride) {
    const float4 v = reinterpret_cast<const float4*>(src)[i];
    ushort4 o;
    o.x = f2bf(v.x); o.y = f2bf(v.y); o.z = f2bf(v.z); o.w = f2bf(v.w);
    reinterpret_cast<ushort4*>(dst)[i] = o;
  }
}

// ---------------- GEMM: C[M,N] = A[M,K] * B[N,K]^T  (bf16 in, f32 out) ----------------
#define BM 128
#define BN 128
#define BK 32

__global__ __launch_bounds__(256) void gemm_bt(const unsigned short* __restrict__ A,
                                               const unsigned short* __restrict__ Bw,
                                               float* __restrict__ C, int M, int N, int K) {
  __shared__ unsigned short Al[BM * BK];
  __shared__ unsigned short Bl[BN * BK];
  const int tid = threadIdx.x;
  const int lane = tid & 63;
  const int wid = tid >> 6;
  const int r = lane & 15, g = lane >> 4;
  const int wm = (wid >> 1) * 64, wn = (wid & 1) * 64;
  const int bm0 = blockIdx.y * BM, bn0 = blockIdx.x * BN;
  const int srow = tid >> 2;          // 0..63
  const int scol = (tid & 3) * 8;     // 0,8,16,24
  f32x4 acc[4][4] = {};
  const size_t abase = (size_t)(bm0 + srow) * K + scol;
  const size_t bbase = (size_t)(bn0 + srow) * K + scol;
  for (int k0 = 0; k0 < K; k0 += BK) {
    bf16x8 a0 = *reinterpret_cast<const bf16x8*>(A + abase + k0);
    bf16x8 a1 = *reinterpret_cast<const bf16x8*>(A + abase + (size_t)64 * K + k0);
    bf16x8 b0 = *reinterpret_cast<const bf16x8*>(Bw + bbase + k0);
    bf16x8 b1 = *reinterpret_cast<const bf16x8*>(Bw + bbase + (size_t)64 * K + k0);
    __syncthreads();
    *reinterpret_cast<bf16x8*>(Al + srow * BK + scol) = a0;
    *reinterpret_cast<bf16x8*>(Al + (64 + srow) * BK + scol) = a1;
    *reinterpret_cast<bf16x8*>(Bl + srow * BK + scol) = b0;
    *reinterpret_cast<bf16x8*>(Bl + (64 + srow) * BK + scol) = b1;
    __syncthreads();
    bf16x8 af[4], bfr[4];
#pragma unroll
    for (int mi = 0; mi < 4; ++mi)
      af[mi] = *reinterpret_cast<const bf16x8*>(Al + (wm + mi * 16 + r) * BK + g * 8);
#pragma unroll
    for (int ni = 0; ni < 4; ++ni)
      bfr[ni] = *reinterpret_cast<const bf16x8*>(Bl + (wn + ni * 16 + r) * BK + g * 8);
#pragma unroll
    for (int mi = 0; mi < 4; ++mi)
#pragma unroll
      for (int ni = 0; ni < 4; ++ni)
        acc[mi][ni] = __builtin_amdgcn_mfma_f32_16x16x32_bf16(af[mi], bfr[ni], acc[mi][ni], 0, 0, 0);
  }
#pragma unroll
  for (int mi = 0; mi < 4; ++mi)
#pragma unroll
    for (int ni = 0; ni < 4; ++ni) {
      const int row = bm0 + wm + mi * 16 + g * 4;
      const int col = bn0 + wn + ni * 16 + r;
#pragma unroll
      for (int e = 0; e < 4; ++e)
        C[(size_t)(row + e) * N + col] = acc[mi][ni][e];
    }
}

// ---------------- postprocess: rotary + rmsnorm on q,k ; gate+ve on v ----------------
// writes Qn [B][NH][T][64] (x QK_SCALE*softmax_scale*log2e), Kn [B][NKV][T][64] (x QK_SCALE),
// Vt [B][NKV][64][T]
__global__ __launch_bounds__(256) void postproc(
    const float* __restrict__ qkv, const float* __restrict__ x, const float* __restrict__ ve,
    const float* __restrict__ cosb, const float* __restrict__ sinb, const float* __restrict__ Wg,
    unsigned short* __restrict__ Qn, unsigned short* __restrict__ Kn, unsigned short* __restrict__ Vt) {
  const int tok = blockIdx.x;
  const int b = tok / T_, t = tok % T_;
  const int wid = threadIdx.x >> 6, lane = threadIdx.x & 63;
  const float* qrow = qkv + (size_t)tok * NQKV;
  const float c = cosb[t * 32 + (lane & 31)];
  const float s = sinb[t * 32 + (lane & 31)];
  for (int u = wid; u < 24; u += 4) {
    if (u < 20) {
      const int off = (u < 16) ? u * 64 : 1024 + (u - 16) * 64;
      float v0 = qrow[off + lane];
      float p = __shfl_xor(v0, 32);
      // lane<32: x1=v0, x2=p -> x1*c + x2*s ; lane>=32: x1=p, x2=v0 -> -x1*s + x2*c
      float rot = (lane < 32) ? (v0 * c + p * s) : (v0 * c - p * s);
      float sq = rot * rot;
#pragma unroll
      for (int m = 1; m < 64; m <<= 1) sq += __shfl_xor(sq, m);
      // Q: 1.2 * (1/8 softmax scale) * log2(e) folded; K: 1.2
      float outv = rot * rsqrtf(sq * (1.0f / 64.0f) + 1.1920929e-7f) *
                   ((u < 16) ? 0.21640425613334453f : 1.2f);
      if (u < 16)
        Qn[((size_t)(b * NH + u) * T_ + t) * HD + lane] = f2bf(outv);
      else
        Kn[((size_t)(b * NKV + (u - 16)) * T_ + t) * HD + lane] = f2bf(outv);
    } else {
      const int kv = u - 20;
      float dot = 0.f;
#pragma unroll
      for (int i = 0; i < 12; ++i) dot += x[(size_t)tok * C_ + i] * Wg[kv * 12 + i];
      const float gate = 3.0f / (1.0f + __expf(-dot));
      const float vv = qrow[1280 + kv * 64 + lane] + gate * ve[(size_t)tok * (NKV * HD) + kv * 64 + lane];
      Vt[((size_t)(b * NKV + kv) * HD + lane) * T_ + t] = f2bf(vv);
    }
  }
}

// ---------------- flash attention, sliding window, GQA ----------------
// grid (T/64, NH, B), 256 thr. Block owns queries [q0, q0+64); wave w owns [q0+16w, +16).
// K/V tiles (64x64 bf16) staged cooperatively in double-buffered, XOR-swizzled LDS
// (colbyte ^= (row&7)<<4). Async-stage split: global loads for tile i+1 issue before
// compute of tile i; ds_writes land after compute; one barrier per iteration.
// S^T = K*Q^T via mfma(A=K,B=Q); O^T += V^T * P^T via mfma(A=V^T fragment, B=P^T).
__global__ __launch_bounds__(256, 4) void attn_fwd(
    const unsigned short* __restrict__ Qn, const unsigned short* __restrict__ Kn,
    const unsigned short* __restrict__ Vt, unsigned short* __restrict__ Y,
    const int* __restrict__ wlp) {
  __shared__ unsigned short Kl[2][KVB * 64];   // [s][d], swizzled, 8KB each
  __shared__ unsigned short Vl[2][64 * KVB];   // [d][s], swizzled, 8KB each
  __shared__ unsigned short Pl[4][16 * 64];    // per-wave P tile, 2KB each
  const int b = blockIdx.z, h = blockIdx.y;
  const int kvh = h >> 2;
  const int tid = threadIdx.x;
  const int wid = tid >> 6, lane = tid & 63;
  const int q0 = blockIdx.x * 64;
  const int qs = q0 + wid * 16;
  const int r = lane & 15, g = lane >> 4;
  const int wl = *wlp;
  const unsigned short* Qb = Qn + ((size_t)(b * NH + h) * T_ + qs) * HD;
  const unsigned short* Kb = Kn + (size_t)(b * NKV + kvh) * T_ * HD;
  const unsigned short* Vb = Vt + (size_t)(b * NKV + kvh) * HD * T_;
  const bf16x8 qf0 = *reinterpret_cast<const bf16x8*>(Qb + r * HD + g * 8);
  const bf16x8 qf1 = *reinterpret_cast<const bf16x8*>(Qb + r * HD + 32 + g * 8);
  float mrun = -1e30f, lrun = 0.f;
  f32x4 o[4] = {};
  int slo = q0 - wl; if (slo < 0) slo = 0;
  slo &= ~63;
  const int send = q0 + 63;
  // staging map: thread covers rows srow, srow+32 of each 64x128B tile
  const int srow = tid >> 3;            // 0..31
  const int scolb = (tid & 7) * 16;     // byte col 0..112
  const int sdst = srow * 128 + (scolb ^ ((srow & 7) << 4));  // swizzled dest byte
  const unsigned short* Ksrc0 = Kb + (size_t)srow * HD + (scolb >> 1);
  const unsigned short* Ksrc1 = Kb + (size_t)(srow + 32) * HD + (scolb >> 1);
  const unsigned short* Vsrc0 = Vb + (size_t)srow * T_ + (scolb >> 1);
  const unsigned short* Vsrc1 = Vb + (size_t)(srow + 32) * T_ + (scolb >> 1);
  char* Pwb = (char*)Pl[wid];
  const int swz = (r & 7) << 4;
  const int ksw = swz;                  // row&7 == r&7 for all fragment rows
  const int q = qs + r;

  // prologue: stage first tile into buf 0
  bf16x8 ska, skb, sva, svb;
  ska = *reinterpret_cast<const bf16x8*>(Ksrc0 + (size_t)slo * HD);
  skb = *reinterpret_cast<const bf16x8*>(Ksrc1 + (size_t)slo * HD);
  sva = *reinterpret_cast<const bf16x8*>(Vsrc0 + slo);
  svb = *reinterpret_cast<const bf16x8*>(Vsrc1 + slo);
  {
    char* Kd = (char*)Kl[0]; char* Vd = (char*)Vl[0];
    *reinterpret_cast<bf16x8*>(Kd + sdst) = ska;
    *reinterpret_cast<bf16x8*>(Kd + 32 * 128 + sdst) = skb;
    *reinterpret_cast<bf16x8*>(Vd + sdst) = sva;
    *reinterpret_cast<bf16x8*>(Vd + 32 * 128 + sdst) = svb;
  }
  __syncthreads();

  int cur = 0;
  for (int sb = slo; sb <= send; sb += KVB) {
    const bool has_next = (sb + KVB <= send);
    if (has_next) {   // issue next tile's global loads early (latency hides under compute)
      const int nb = sb + KVB;
      ska = *reinterpret_cast<const bf16x8*>(Ksrc0 + (size_t)nb * HD);
      skb = *reinterpret_cast<const bf16x8*>(Ksrc1 + (size_t)nb * HD);
      sva = *reinterpret_cast<const bf16x8*>(Vsrc0 + nb);
      svb = *reinterpret_cast<const bf16x8*>(Vsrc1 + nb);
    }
    if (sb <= qs + 15) {   // wave participates in this key-block
      const char* Kc = (const char*)Kl[cur];
      const char* Vc = (const char*)Vl[cur];
      float sv[16];
#pragma unroll
      for (int sub = 0; sub < 4; ++sub) {
        const int rowb = (sub * 16 + r) * 128;
        bf16x8 kf0 = *reinterpret_cast<const bf16x8*>(Kc + rowb + ((g * 16) ^ ksw));
        bf16x8 kf1 = *reinterpret_cast<const bf16x8*>(Kc + rowb + ((64 + g * 16) ^ ksw));
        f32x4 z = {};
        z = __builtin_amdgcn_mfma_f32_16x16x32_bf16(kf0, qf0, z, 0, 0, 0);
        z = __builtin_amdgcn_mfma_f32_16x16x32_bf16(kf1, qf1, z, 0, 0, 0);
#pragma unroll
        for (int e = 0; e < 4; ++e) sv[sub * 4 + e] = z[e];
      }
      // edge blocks only: causal edge or window edge
      if (sb + 63 > qs || sb < qs + 15 - wl) {
#pragma unroll
        for (int i = 0; i < 16; ++i) {
          const int s_ = sb + (i >> 2) * 16 + g * 4 + (i & 3);
          const bool ok = (unsigned)(q - s_) <= (unsigned)wl;  // 0 <= q-s_ <= wl
          sv[i] = ok ? sv[i] : -__builtin_inff();
        }
      }
      float pm = sv[0];
#pragma unroll
      for (int i = 1; i < 16; ++i) pm = fmaxf(pm, sv[i]);
      pm = fmaxf(pm, __shfl_xor(pm, 16));
      pm = fmaxf(pm, __shfl_xor(pm, 32));
      if (!__all(pm <= mrun + 8.0f)) {          // defer-max (THR=8 in log2 units)
        const float mnew = fmaxf(mrun, pm);
        const float scl = exp2f(mrun - mnew);
        lrun *= scl;
#pragma unroll
        for (int dt = 0; dt < 4; ++dt)
#pragma unroll
          for (int e = 0; e < 4; ++e) o[dt][e] *= scl;
        mrun = mnew;
      }
      float ps = 0.f;
      unsigned short pb[16];
#pragma unroll
      for (int i = 0; i < 16; ++i) {
        const float p = exp2f(sv[i] - mrun);    // scores pre-scaled by log2(e)
        ps += p;
        pb[i] = f2bf(p);
      }
      ps += __shfl_xor(ps, 16);
      ps += __shfl_xor(ps, 32);
      lrun += ps;
      // store P^T tile [q=r][s 0..63] to swizzled per-wave LDS
#pragma unroll
      for (int sub = 0; sub < 4; ++sub) {
        bf16x4 w;
#pragma unroll
        for (int e = 0; e < 4; ++e) w[e] = (short)pb[sub * 4 + e];
        *reinterpret_cast<bf16x4*>(Pwb + ((r * 128 + sub * 32 + g * 8) ^ swz)) = w;
      }
      asm volatile("s_waitcnt lgkmcnt(0)" ::: "memory");
#pragma unroll
      for (int c = 0; c < 2; ++c) {
        const bf16x8 pf = *reinterpret_cast<const bf16x8*>(Pwb + ((r * 128 + c * 64 + g * 16) ^ swz));
#pragma unroll
        for (int dt = 0; dt < 4; ++dt) {
          const int vrow = (dt * 16 + r) * 128;
          const bf16x8 vf = *reinterpret_cast<const bf16x8*>(Vc + vrow + ((c * 64 + g * 16) ^ ksw));
          o[dt] = __builtin_amdgcn_mfma_f32_16x16x32_bf16(vf, pf, o[dt], 0, 0, 0);
        }
      }
    }
    if (has_next) {   // write staged tile to the other buffer (vmcnt wait auto-inserted)
      char* Kd = (char*)Kl[cur ^ 1]; char* Vd = (char*)Vl[cur ^ 1];
      *reinterpret_cast<bf16x8*>(Kd + sdst) = ska;
      *reinterpret_cast<bf16x8*>(Kd + 32 * 128 + sdst) = skb;
      *reinterpret_cast<bf16x8*>(Vd + sdst) = sva;
      *reinterpret_cast<bf16x8*>(Vd + 32 * 128 + sdst) = svb;
    }
    __syncthreads();
    cur ^= 1;
  }
  const float inv = 1.0f / lrun;
  unsigned short* Yb = Y + ((size_t)(b * T_) + qs + r) * (NH * HD) + h * HD;
#pragma unroll
  for (int dt = 0; dt < 4; ++dt)
#pragma unroll
    for (int e = 0; e < 4; ++e)
      Yb[dt * 16 + g * 4 + e] = f2bf(o[dt][e] * inv);
}

extern "C" void kernel_launch(void* const* d_in, const int* in_sizes, int n_in,
                              void* d_out, int out_size, void* d_ws, size_t ws_size,
                              hipStream_t stream) {
  const float* x    = (const float*)d_in[0];
  const float* ve   = (const float*)d_in[1];
  const float* cosb = (const float*)d_in[2];
  const float* sinb = (const float*)d_in[3];
  const float* Wq   = (const float*)d_in[4];
  const float* Wk   = (const float*)d_in[5];
  const float* Wv   = (const float*)d_in[6];
  const float* Wo   = (const float*)d_in[7];
  const float* Wg   = (const float*)d_in[8];
  const int*   wlp  = (const int*)d_in[9];

  char* ws = (char*)d_ws;
  unsigned short* xb    = (unsigned short*)ws; ws += (size_t)4096 * 1024 * 2;
  unsigned short* wqkvb = (unsigned short*)ws; ws += (size_t)1536 * 1024 * 2;
  unsigned short* wob   = (unsigned short*)ws; ws += (size_t)1024 * 1024 * 2;
  float*          qkv   = (float*)ws;          ws += (size_t)4096 * 1536 * 4;
  unsigned short* Qn    = (unsigned short*)ws; ws += (size_t)B_ * NH * T_ * HD * 2;
  unsigned short* Kn    = (unsigned short*)ws; ws += (size_t)B_ * NKV * T_ * HD * 2;
  unsigned short* Vt    = (unsigned short*)ws; ws += (size_t)B_ * NKV * HD * T_ * 2;
  unsigned short* yb    = (unsigned short*)ws; ws += (size_t)4096 * 1024 * 2;

  conv_bf16<<<dim3(1024), dim3(256), 0, stream>>>(x, xb, 4096 * 1024 / 4);
  conv_bf16<<<dim3(512), dim3(256), 0, stream>>>(Wq, wqkvb, 1024 * 1024 / 4);
  conv_bf16<<<dim3(128), dim3(256), 0, stream>>>(Wk, wqkvb + (size_t)1024 * 1024, 256 * 1024 / 4);
  conv_bf16<<<dim3(128), dim3(256), 0, stream>>>(Wv, wqkvb + (size_t)1280 * 1024, 256 * 1024 / 4);
  conv_bf16<<<dim3(512), dim3(256), 0, stream>>>(Wo, wob, 1024 * 1024 / 4);

  gemm_bt<<<dim3(NQKV / BN, 4096 / BM), dim3(256), 0, stream>>>(xb, wqkvb, qkv, 4096, NQKV, 1024);

  postproc<<<dim3(4096), dim3(256), 0, stream>>>(qkv, x, ve, cosb, sinb, Wg, Qn, Kn, Vt);

  attn_fwd<<<dim3(T_ / 64, NH, B_), dim3(256), 0, stream>>>(Qn, Kn, Vt, yb, wlp);

  gemm_bt<<<dim3(1024 / BN, 4096 / BM), dim3(256), 0, stream>>>(yb, wob, (float*)d_out, 4096, 1024, 1024);
}

// Round 4
// 127.425 us; speedup vs baseline: 1.6900x; 1.0858x over previous
//
#include <hip/hip_runtime.h>
#include <hip/hip_bf16.h>

#define B_ 2
#define T_ 2048
#define C_ 1024
#define NH 16
#define NKV 4
#define HD 64
#define NQKV 1536
#define KVB 64

typedef __attribute__((ext_vector_type(4))) float f32x4;
typedef __attribute__((ext_vector_type(8))) short bf16x8;
typedef __attribute__((ext_vector_type(4))) short bf16x4;

__device__ __forceinline__ unsigned short f2bf(float f) {
  unsigned u = __float_as_uint(f);
  u = (u + 0x7fffu + ((u >> 16) & 1u)) >> 16;
  return (unsigned short)u;
}

__device__ __forceinline__ void gload16(const void* g, void* l) {
  __builtin_amdgcn_global_load_lds(
      (const __attribute__((address_space(1))) void*)g,
      (__attribute__((address_space(3))) void*)l, 16, 0, 0);
}

// ---------------- f32 -> bf16 convert (vectorized, grid-stride) ----------------
__global__ __launch_bounds__(256) void conv_bf16(const float* __restrict__ src,
                                                 unsigned short* __restrict__ dst, int n4) {
  int i = blockIdx.x * blockDim.x + threadIdx.x;
  const int stride = gridDim.x * blockDim.x;
  for (; i < n4; i += stride) {
    const float4 v = reinterpret_cast<const float4*>(src)[i];
    ushort4 o;
    o.x = f2bf(v.x); o.y = f2bf(v.y); o.z = f2bf(v.z); o.w = f2bf(v.w);
    reinterpret_cast<ushort4*>(dst)[i] = o;
  }
}

// ---------------- GEMM: C[M,N] = A[M,K] * B[N,K]^T  (bf16 in, f32 out) ----------------
// m97 structure: 128x128 tile, BK=64, global_load_lds width-16 staging, single LDS buffer,
// 2 barriers per K-step. Bank-conflict fix per rule 21: LDS dest linear, global SOURCE
// pre-swizzled (lane fetches col ((l&7)^(l>>3))*8), ds_read applies colb ^= (row&7)<<4.
#define BM 128
#define BN 128
#define BK 64

__global__ __launch_bounds__(256) void gemm_bt(const unsigned short* __restrict__ A,
                                               const unsigned short* __restrict__ Bw,
                                               float* __restrict__ C, int M, int N, int K) {
  __shared__ unsigned short Al[BM * BK];   // [row][64] bf16, row stride 128B
  __shared__ unsigned short Bl[BN * BK];
  const int tid = threadIdx.x;
  const int lane = tid & 63;
  const int wid = tid >> 6;
  const int r = lane & 15, g = lane >> 4;
  const int wm = (wid >> 1) * 64, wn = (wid & 1) * 64;
  const int bm0 = blockIdx.y * BM, bn0 = blockIdx.x * BN;
  // staging: lane l covers row (l>>3), source col pre-swizzled so LDS holds
  // LDS[row][colb] = global[row][colb ^ ((row&7)<<4)]
  const int lrow = lane >> 3;                    // 0..7
  const int lcol = ((lane & 7) ^ lrow) * 8;      // swizzled source element col
  const unsigned short* Asrc = A + (size_t)(bm0 + wid * 32 + lrow) * K + lcol;
  const unsigned short* Bsrc = Bw + (size_t)(bn0 + wid * 32 + lrow) * K + lcol;
  const int fsw = (r & 7) << 4;
  const char* Ac = (const char*)Al;
  const char* Bc = (const char*)Bl;
  f32x4 acc[4][4] = {};
  for (int k0 = 0; k0 < K; k0 += BK) {
    __syncthreads();   // previous K-step's reads done before overwrite
#pragma unroll
    for (int i = 0; i < 4; ++i) {
      gload16(Asrc + (size_t)(i * 8) * K + k0, Al + (wid * 32 + i * 8) * BK);
      gload16(Bsrc + (size_t)(i * 8) * K + k0, Bl + (wid * 32 + i * 8) * BK);
    }
    __syncthreads();   // compiler drains vmcnt(0) before barrier
    bf16x8 af[4][2], bfr[4][2];
#pragma unroll
    for (int mi = 0; mi < 4; ++mi)
#pragma unroll
      for (int s = 0; s < 2; ++s)
        af[mi][s] = *reinterpret_cast<const bf16x8*>(
            Ac + (wm + mi * 16 + r) * 128 + ((s * 64 + g * 16) ^ fsw));
#pragma unroll
    for (int ni = 0; ni < 4; ++ni)
#pragma unroll
      for (int s = 0; s < 2; ++s)
        bfr[ni][s] = *reinterpret_cast<const bf16x8*>(
            Bc + (wn + ni * 16 + r) * 128 + ((s * 64 + g * 16) ^ fsw));
#pragma unroll
    for (int s = 0; s < 2; ++s)
#pragma unroll
      for (int mi = 0; mi < 4; ++mi)
#pragma unroll
        for (int ni = 0; ni < 4; ++ni)
          acc[mi][ni] = __builtin_amdgcn_mfma_f32_16x16x32_bf16(af[mi][s], bfr[ni][s],
                                                                acc[mi][ni], 0, 0, 0);
  }
#pragma unroll
  for (int mi = 0; mi < 4; ++mi)
#pragma unroll
    for (int ni = 0; ni < 4; ++ni) {
      const int row = bm0 + wm + mi * 16 + g * 4;
      const int col = bn0 + wn + ni * 16 + r;
#pragma unroll
      for (int e = 0; e < 4; ++e)
        C[(size_t)(row + e) * N + col] = acc[mi][ni][e];
    }
}

// ---------------- postprocess: rotary + rmsnorm on q,k ; gate+ve on v ----------------
// writes Qn [B][NH][T][64] (x QK_SCALE*softmax_scale*log2e), Kn [B][NKV][T][64] (x QK_SCALE),
// Vt [B][NKV][64][T]
__global__ __launch_bounds__(256) void postproc(
    const float* __restrict__ qkv, const float* __restrict__ x, const float* __restrict__ ve,
    const float* __restrict__ cosb, const float* __restrict__ sinb, const float* __restrict__ Wg,
    unsigned short* __restrict__ Qn, unsigned short* __restrict__ Kn, unsigned short* __restrict__ Vt) {
  const int tok = blockIdx.x;
  const int b = tok / T_, t = tok % T_;
  const int wid = threadIdx.x >> 6, lane = threadIdx.x & 63;
  const float* qrow = qkv + (size_t)tok * NQKV;
  const float c = cosb[t * 32 + (lane & 31)];
  const float s = sinb[t * 32 + (lane & 31)];
  for (int u = wid; u < 24; u += 4) {
    if (u < 20) {
      const int off = (u < 16) ? u * 64 : 1024 + (u - 16) * 64;
      float v0 = qrow[off + lane];
      float p = __shfl_xor(v0, 32);
      // lane<32: x1=v0, x2=p -> x1*c + x2*s ; lane>=32: x1=p, x2=v0 -> -x1*s + x2*c
      float rot = (lane < 32) ? (v0 * c + p * s) : (v0 * c - p * s);
      float sq = rot * rot;
#pragma unroll
      for (int m = 1; m < 64; m <<= 1) sq += __shfl_xor(sq, m);
      // Q: 1.2 * (1/8 softmax scale) * log2(e) folded; K: 1.2
      float outv = rot * rsqrtf(sq * (1.0f / 64.0f) + 1.1920929e-7f) *
                   ((u < 16) ? 0.21640425613334453f : 1.2f);
      if (u < 16)
        Qn[((size_t)(b * NH + u) * T_ + t) * HD + lane] = f2bf(outv);
      else
        Kn[((size_t)(b * NKV + (u - 16)) * T_ + t) * HD + lane] = f2bf(outv);
    } else {
      const int kv = u - 20;
      float dot = 0.f;
#pragma unroll
      for (int i = 0; i < 12; ++i) dot += x[(size_t)tok * C_ + i] * Wg[kv * 12 + i];
      const float gate = 3.0f / (1.0f + __expf(-dot));
      const float vv = qrow[1280 + kv * 64 + lane] + gate * ve[(size_t)tok * (NKV * HD) + kv * 64 + lane];
      Vt[((size_t)(b * NKV + kv) * HD + lane) * T_ + t] = f2bf(vv);
    }
  }
}

// ---------------- flash attention, sliding window, GQA ----------------
// grid (T/64, NH, B), 256 thr. Block owns queries [q0, q0+64); wave w owns [q0+16w, +16).
// K/V tiles (64x64 bf16) staged cooperatively in double-buffered, XOR-swizzled LDS
// (colbyte ^= (row&7)<<4). Async-stage split: global loads for tile i+1 issue before
// compute of tile i; ds_writes land after compute; one barrier per iteration.
// S^T = K*Q^T via mfma(A=K,B=Q); O^T += V^T * P^T via mfma(A=V^T fragment, B=P^T).
__global__ __launch_bounds__(256, 4) void attn_fwd(
    const unsigned short* __restrict__ Qn, const unsigned short* __restrict__ Kn,
    const unsigned short* __restrict__ Vt, unsigned short* __restrict__ Y,
    const int* __restrict__ wlp) {
  __shared__ unsigned short Kl[2][KVB * 64];   // [s][d], swizzled, 8KB each
  __shared__ unsigned short Vl[2][64 * KVB];   // [d][s], swizzled, 8KB each
  __shared__ unsigned short Pl[4][16 * 64];    // per-wave P tile, 2KB each
  const int b = blockIdx.z, h = blockIdx.y;
  const int kvh = h >> 2;
  const int tid = threadIdx.x;
  const int wid = tid >> 6, lane = tid & 63;
  const int q0 = blockIdx.x * 64;
  const int qs = q0 + wid * 16;
  const int r = lane & 15, g = lane >> 4;
  const int wl = *wlp;
  const unsigned short* Qb = Qn + ((size_t)(b * NH + h) * T_ + qs) * HD;
  const unsigned short* Kb = Kn + (size_t)(b * NKV + kvh) * T_ * HD;
  const unsigned short* Vb = Vt + (size_t)(b * NKV + kvh) * HD * T_;
  const bf16x8 qf0 = *reinterpret_cast<const bf16x8*>(Qb + r * HD + g * 8);
  const bf16x8 qf1 = *reinterpret_cast<const bf16x8*>(Qb + r * HD + 32 + g * 8);
  float mrun = -1e30f, lrun = 0.f;
  f32x4 o[4] = {};
  int slo = q0 - wl; if (slo < 0) slo = 0;
  slo &= ~63;
  const int send = q0 + 63;
  // staging map: thread covers rows srow, srow+32 of each 64x128B tile
  const int srow = tid >> 3;            // 0..31
  const int scolb = (tid & 7) * 16;     // byte col 0..112
  const int sdst = srow * 128 + (scolb ^ ((srow & 7) << 4));  // swizzled dest byte
  const unsigned short* Ksrc0 = Kb + (size_t)srow * HD + (scolb >> 1);
  const unsigned short* Ksrc1 = Kb + (size_t)(srow + 32) * HD + (scolb >> 1);
  const unsigned short* Vsrc0 = Vb + (size_t)srow * T_ + (scolb >> 1);
  const unsigned short* Vsrc1 = Vb + (size_t)(srow + 32) * T_ + (scolb >> 1);
  char* Pwb = (char*)Pl[wid];
  const int swz = (r & 7) << 4;
  const int ksw = swz;                  // row&7 == r&7 for all fragment rows
  const int q = qs + r;

  // prologue: stage first tile into buf 0
  bf16x8 ska, skb, sva, svb;
  ska = *reinterpret_cast<const bf16x8*>(Ksrc0 + (size_t)slo * HD);
  skb = *reinterpret_cast<const bf16x8*>(Ksrc1 + (size_t)slo * HD);
  sva = *reinterpret_cast<const bf16x8*>(Vsrc0 + slo);
  svb = *reinterpret_cast<const bf16x8*>(Vsrc1 + slo);
  {
    char* Kd = (char*)Kl[0]; char* Vd = (char*)Vl[0];
    *reinterpret_cast<bf16x8*>(Kd + sdst) = ska;
    *reinterpret_cast<bf16x8*>(Kd + 32 * 128 + sdst) = skb;
    *reinterpret_cast<bf16x8*>(Vd + sdst) = sva;
    *reinterpret_cast<bf16x8*>(Vd + 32 * 128 + sdst) = svb;
  }
  __syncthreads();

  int cur = 0;
  for (int sb = slo; sb <= send; sb += KVB) {
    const bool has_next = (sb + KVB <= send);
    if (has_next) {   // issue next tile's global loads early (latency hides under compute)
      const int nb = sb + KVB;
      ska = *reinterpret_cast<const bf16x8*>(Ksrc0 + (size_t)nb * HD);
      skb = *reinterpret_cast<const bf16x8*>(Ksrc1 + (size_t)nb * HD);
      sva = *reinterpret_cast<const bf16x8*>(Vsrc0 + nb);
      svb = *reinterpret_cast<const bf16x8*>(Vsrc1 + nb);
    }
    if (sb <= qs + 15) {   // wave participates in this key-block
      const char* Kc = (const char*)Kl[cur];
      const char* Vc = (const char*)Vl[cur];
      float sv[16];
#pragma unroll
      for (int sub = 0; sub < 4; ++sub) {
        const int rowb = (sub * 16 + r) * 128;
        bf16x8 kf0 = *reinterpret_cast<const bf16x8*>(Kc + rowb + ((g * 16) ^ ksw));
        bf16x8 kf1 = *reinterpret_cast<const bf16x8*>(Kc + rowb + ((64 + g * 16) ^ ksw));
        f32x4 z = {};
        z = __builtin_amdgcn_mfma_f32_16x16x32_bf16(kf0, qf0, z, 0, 0, 0);
        z = __builtin_amdgcn_mfma_f32_16x16x32_bf16(kf1, qf1, z, 0, 0, 0);
#pragma unroll
        for (int e = 0; e < 4; ++e) sv[sub * 4 + e] = z[e];
      }
      // edge blocks only: causal edge or window edge
      if (sb + 63 > qs || sb < qs + 15 - wl) {
#pragma unroll
        for (int i = 0; i < 16; ++i) {
          const int s_ = sb + (i >> 2) * 16 + g * 4 + (i & 3);
          const bool ok = (unsigned)(q - s_) <= (unsigned)wl;  // 0 <= q-s_ <= wl
          sv[i] = ok ? sv[i] : -__builtin_inff();
        }
      }
      float pm = sv[0];
#pragma unroll
      for (int i = 1; i < 16; ++i) pm = fmaxf(pm, sv[i]);
      pm = fmaxf(pm, __shfl_xor(pm, 16));
      pm = fmaxf(pm, __shfl_xor(pm, 32));
      if (!__all(pm <= mrun + 8.0f)) {          // defer-max (THR=8 in log2 units)
        const float mnew = fmaxf(mrun, pm);
        const float scl = exp2f(mrun - mnew);
        lrun *= scl;
#pragma unroll
        for (int dt = 0; dt < 4; ++dt)
#pragma unroll
          for (int e = 0; e < 4; ++e) o[dt][e] *= scl;
        mrun = mnew;
      }
      float ps = 0.f;
      unsigned short pb[16];
#pragma unroll
      for (int i = 0; i < 16; ++i) {
        const float p = exp2f(sv[i] - mrun);    // scores pre-scaled by log2(e)
        ps += p;
        pb[i] = f2bf(p);
      }
      ps += __shfl_xor(ps, 16);
      ps += __shfl_xor(ps, 32);
      lrun += ps;
      // store P^T tile [q=r][s 0..63] to swizzled per-wave LDS
#pragma unroll
      for (int sub = 0; sub < 4; ++sub) {
        bf16x4 w;
#pragma unroll
        for (int e = 0; e < 4; ++e) w[e] = (short)pb[sub * 4 + e];
        *reinterpret_cast<bf16x4*>(Pwb + ((r * 128 + sub * 32 + g * 8) ^ swz)) = w;
      }
      asm volatile("s_waitcnt lgkmcnt(0)" ::: "memory");
#pragma unroll
      for (int c = 0; c < 2; ++c) {
        const bf16x8 pf = *reinterpret_cast<const bf16x8*>(Pwb + ((r * 128 + c * 64 + g * 16) ^ swz));
#pragma unroll
        for (int dt = 0; dt < 4; ++dt) {
          const int vrow = (dt * 16 + r) * 128;
          const bf16x8 vf = *reinterpret_cast<const bf16x8*>(Vc + vrow + ((c * 64 + g * 16) ^ ksw));
          o[dt] = __builtin_amdgcn_mfma_f32_16x16x32_bf16(vf, pf, o[dt], 0, 0, 0);
        }
      }
    }
    if (has_next) {   // write staged tile to the other buffer (vmcnt wait auto-inserted)
      char* Kd = (char*)Kl[cur ^ 1]; char* Vd = (char*)Vl[cur ^ 1];
      *reinterpret_cast<bf16x8*>(Kd + sdst) = ska;
      *reinterpret_cast<bf16x8*>(Kd + 32 * 128 + sdst) = skb;
      *reinterpret_cast<bf16x8*>(Vd + sdst) = sva;
      *reinterpret_cast<bf16x8*>(Vd + 32 * 128 + sdst) = svb;
    }
    __syncthreads();
    cur ^= 1;
  }
  const float inv = 1.0f / lrun;
  unsigned short* Yb = Y + ((size_t)(b * T_) + qs + r) * (NH * HD) + h * HD;
#pragma unroll
  for (int dt = 0; dt < 4; ++dt)
#pragma unroll
    for (int e = 0; e < 4; ++e)
      Yb[dt * 16 + g * 4 + e] = f2bf(o[dt][e] * inv);
}

extern "C" void kernel_launch(void* const* d_in, const int* in_sizes, int n_in,
                              void* d_out, int out_size, void* d_ws, size_t ws_size,
                              hipStream_t stream) {
  const float* x    = (const float*)d_in[0];
  const float* ve   = (const float*)d_in[1];
  const float* cosb = (const float*)d_in[2];
  const float* sinb = (const float*)d_in[3];
  const float* Wq   = (const float*)d_in[4];
  const float* Wk   = (const float*)d_in[5];
  const float* Wv   = (const float*)d_in[6];
  const float* Wo   = (const float*)d_in[7];
  const float* Wg   = (const float*)d_in[8];
  const int*   wlp  = (const int*)d_in[9];

  char* ws = (char*)d_ws;
  unsigned short* xb    = (unsigned short*)ws; ws += (size_t)4096 * 1024 * 2;
  unsigned short* wqkvb = (unsigned short*)ws; ws += (size_t)1536 * 1024 * 2;
  unsigned short* wob   = (unsigned short*)ws; ws += (size_t)1024 * 1024 * 2;
  float*          qkv   = (float*)ws;          ws += (size_t)4096 * 1536 * 4;
  unsigned short* Qn    = (unsigned short*)ws; ws += (size_t)B_ * NH * T_ * HD * 2;
  unsigned short* Kn    = (unsigned short*)ws; ws += (size_t)B_ * NKV * T_ * HD * 2;
  unsigned short* Vt    = (unsigned short*)ws; ws += (size_t)B_ * NKV * HD * T_ * 2;
  unsigned short* yb    = (unsigned short*)ws; ws += (size_t)4096 * 1024 * 2;

  conv_bf16<<<dim3(1024), dim3(256), 0, stream>>>(x, xb, 4096 * 1024 / 4);
  conv_bf16<<<dim3(512), dim3(256), 0, stream>>>(Wq, wqkvb, 1024 * 1024 / 4);
  conv_bf16<<<dim3(128), dim3(256), 0, stream>>>(Wk, wqkvb + (size_t)1024 * 1024, 256 * 1024 / 4);
  conv_bf16<<<dim3(128), dim3(256), 0, stream>>>(Wv, wqkvb + (size_t)1280 * 1024, 256 * 1024 / 4);
  conv_bf16<<<dim3(512), dim3(256), 0, stream>>>(Wo, wob, 1024 * 1024 / 4);

  gemm_bt<<<dim3(NQKV / BN, 4096 / BM), dim3(256), 0, stream>>>(xb, wqkvb, qkv, 4096, NQKV, 1024);

  postproc<<<dim3(4096), dim3(256), 0, stream>>>(qkv, x, ve, cosb, sinb, Wg, Qn, Kn, Vt);

  attn_fwd<<<dim3(T_ / 64, NH, B_), dim3(256), 0, stream>>>(Qn, Kn, Vt, yb, wlp);

  gemm_bt<<<dim3(1024 / BN, 4096 / BM), dim3(256), 0, stream>>>(yb, wob, (float*)d_out, 4096, 1024, 1024);
}

// Round 5
// 117.349 us; speedup vs baseline: 1.8352x; 1.0859x over previous
//
#include <hip/hip_runtime.h>
#include <hip/hip_bf16.h>

#define B_ 2
#define T_ 2048
#define C_ 1024
#define NH 16
#define NKV 4
#define HD 64
#define NQKV 1536
#define KVB 64

typedef __attribute__((ext_vector_type(4))) float f32x4;
typedef __attribute__((ext_vector_type(8))) short bf16x8;
typedef __attribute__((ext_vector_type(4))) short bf16x4;

__device__ __forceinline__ unsigned short f2bf(float f) {
  __hip_bfloat16 h = __float2bfloat16(f);   // RNE; compiler emits native cvt (pk-fusable)
  unsigned short u;
  __builtin_memcpy(&u, &h, 2);
  return u;
}

__device__ __forceinline__ void gload16(const void* g, void* l) {
  __builtin_amdgcn_global_load_lds(
      (const __attribute__((address_space(1))) void*)g,
      (__attribute__((address_space(3))) void*)l, 16, 0, 0);
}

// ---------------- fused f32 -> bf16 convert for all 5 tensors (1 launch) ----------------
#define NX4  1048576   // x      : 4096*1024/4
#define NW4  262144    // Wq / Wo: 1024*1024/4
#define NK4  65536     // Wk / Wv:  256*1024/4
#define O1 (NX4)
#define O2 (O1 + NW4)
#define O3 (O2 + NK4)
#define O4 (O3 + NK4)
#define OT (O4 + NW4)

__global__ __launch_bounds__(256) void conv_all(
    const float* __restrict__ x, const float* __restrict__ wq, const float* __restrict__ wk,
    const float* __restrict__ wv, const float* __restrict__ wo,
    unsigned short* __restrict__ xb, unsigned short* __restrict__ wqkvb,
    unsigned short* __restrict__ wob) {
  int i = blockIdx.x * blockDim.x + threadIdx.x;
  const int stride = gridDim.x * blockDim.x;
  for (; i < OT; i += stride) {
    const float* src;
    unsigned short* dst;
    int j;
    if (i < O1)      { src = x;  dst = xb;                    j = i; }
    else if (i < O2) { src = wq; dst = wqkvb;                 j = i - O1; }
    else if (i < O3) { src = wk; dst = wqkvb + 1024 * 1024;   j = i - O2; }
    else if (i < O4) { src = wv; dst = wqkvb + 1280 * 1024;   j = i - O3; }
    else             { src = wo; dst = wob;                   j = i - O4; }
    const float4 v = reinterpret_cast<const float4*>(src)[j];
    ushort4 o;
    o.x = f2bf(v.x); o.y = f2bf(v.y); o.z = f2bf(v.z); o.w = f2bf(v.w);
    reinterpret_cast<ushort4*>(dst)[j] = o;
  }
}

// ---------------- GEMM: C[M,N] = A[M,K] * B[N,K]^T  (bf16 in, f32 out) ----------------
// m97 structure: 128x128 tile, BK=64, global_load_lds width-16 staging, single LDS buffer,
// 2 barriers per K-step. Bank-conflict fix per rule 21: LDS dest linear, global SOURCE
// pre-swizzled (lane fetches col ((l&7)^(l>>3))*8), ds_read applies colb ^= (row&7)<<4.
#define BM 128
#define BN 128
#define BK 64

__global__ __launch_bounds__(256) void gemm_bt(const unsigned short* __restrict__ A,
                                               const unsigned short* __restrict__ Bw,
                                               float* __restrict__ C, int M, int N, int K) {
  __shared__ unsigned short Al[BM * BK];   // [row][64] bf16, row stride 128B
  __shared__ unsigned short Bl[BN * BK];
  const int tid = threadIdx.x;
  const int lane = tid & 63;
  const int wid = tid >> 6;
  const int r = lane & 15, g = lane >> 4;
  const int wm = (wid >> 1) * 64, wn = (wid & 1) * 64;
  const int bm0 = blockIdx.y * BM, bn0 = blockIdx.x * BN;
  // staging: lane l covers row (l>>3), source col pre-swizzled so LDS holds
  // LDS[row][colb] = global[row][colb ^ ((row&7)<<4)]
  const int lrow = lane >> 3;                    // 0..7
  const int lcol = ((lane & 7) ^ lrow) * 8;      // swizzled source element col
  const unsigned short* Asrc = A + (size_t)(bm0 + wid * 32 + lrow) * K + lcol;
  const unsigned short* Bsrc = Bw + (size_t)(bn0 + wid * 32 + lrow) * K + lcol;
  const int fsw = (r & 7) << 4;
  const char* Ac = (const char*)Al;
  const char* Bc = (const char*)Bl;
  f32x4 acc[4][4] = {};
  for (int k0 = 0; k0 < K; k0 += BK) {
    __syncthreads();   // previous K-step's reads done before overwrite
#pragma unroll
    for (int i = 0; i < 4; ++i) {
      gload16(Asrc + (size_t)(i * 8) * K + k0, Al + (wid * 32 + i * 8) * BK);
      gload16(Bsrc + (size_t)(i * 8) * K + k0, Bl + (wid * 32 + i * 8) * BK);
    }
    __syncthreads();   // compiler drains vmcnt(0) before barrier
    bf16x8 af[4][2], bfr[4][2];
#pragma unroll
    for (int mi = 0; mi < 4; ++mi)
#pragma unroll
      for (int s = 0; s < 2; ++s)
        af[mi][s] = *reinterpret_cast<const bf16x8*>(
            Ac + (wm + mi * 16 + r) * 128 + ((s * 64 + g * 16) ^ fsw));
#pragma unroll
    for (int ni = 0; ni < 4; ++ni)
#pragma unroll
      for (int s = 0; s < 2; ++s)
        bfr[ni][s] = *reinterpret_cast<const bf16x8*>(
            Bc + (wn + ni * 16 + r) * 128 + ((s * 64 + g * 16) ^ fsw));
#pragma unroll
    for (int s = 0; s < 2; ++s)
#pragma unroll
      for (int mi = 0; mi < 4; ++mi)
#pragma unroll
        for (int ni = 0; ni < 4; ++ni)
          acc[mi][ni] = __builtin_amdgcn_mfma_f32_16x16x32_bf16(af[mi][s], bfr[ni][s],
                                                                acc[mi][ni], 0, 0, 0);
  }
#pragma unroll
  for (int mi = 0; mi < 4; ++mi)
#pragma unroll
    for (int ni = 0; ni < 4; ++ni) {
      const int row = bm0 + wm + mi * 16 + g * 4;
      const int col = bn0 + wn + ni * 16 + r;
#pragma unroll
      for (int e = 0; e < 4; ++e)
        C[(size_t)(row + e) * N + col] = acc[mi][ni][e];
    }
}

// ---------------- postprocess: rotary + rmsnorm on q,k ; gate+ve on v ----------------
// writes Qn [B][NH][T][64] (x QK_SCALE*softmax_scale*log2e), Kn [B][NKV][T][64] (x QK_SCALE),
// Vt [B][NKV][64][T]
__global__ __launch_bounds__(256) void postproc(
    const float* __restrict__ qkv, const float* __restrict__ x, const float* __restrict__ ve,
    const float* __restrict__ cosb, const float* __restrict__ sinb, const float* __restrict__ Wg,
    unsigned short* __restrict__ Qn, unsigned short* __restrict__ Kn, unsigned short* __restrict__ Vt) {
  const int tok = blockIdx.x;
  const int b = tok / T_, t = tok % T_;
  const int wid = threadIdx.x >> 6, lane = threadIdx.x & 63;
  const float* qrow = qkv + (size_t)tok * NQKV;
  const float c = cosb[t * 32 + (lane & 31)];
  const float s = sinb[t * 32 + (lane & 31)];
  for (int u = wid; u < 24; u += 4) {
    if (u < 20) {
      const int off = (u < 16) ? u * 64 : 1024 + (u - 16) * 64;
      float v0 = qrow[off + lane];
      float p = __shfl_xor(v0, 32);
      // lane<32: x1=v0, x2=p -> x1*c + x2*s ; lane>=32: x1=p, x2=v0 -> -x1*s + x2*c
      float rot = (lane < 32) ? (v0 * c + p * s) : (v0 * c - p * s);
      float sq = rot * rot;
#pragma unroll
      for (int m = 1; m < 64; m <<= 1) sq += __shfl_xor(sq, m);
      // Q: 1.2 * (1/8 softmax scale) * log2(e) folded; K: 1.2
      float outv = rot * rsqrtf(sq * (1.0f / 64.0f) + 1.1920929e-7f) *
                   ((u < 16) ? 0.21640425613334453f : 1.2f);
      if (u < 16)
        Qn[((size_t)(b * NH + u) * T_ + t) * HD + lane] = f2bf(outv);
      else
        Kn[((size_t)(b * NKV + (u - 16)) * T_ + t) * HD + lane] = f2bf(outv);
    } else {
      const int kv = u - 20;
      float dot = 0.f;
#pragma unroll
      for (int i = 0; i < 12; ++i) dot += x[(size_t)tok * C_ + i] * Wg[kv * 12 + i];
      const float gate = 3.0f / (1.0f + __expf(-dot));
      const float vv = qrow[1280 + kv * 64 + lane] + gate * ve[(size_t)tok * (NKV * HD) + kv * 64 + lane];
      Vt[((size_t)(b * NKV + kv) * HD + lane) * T_ + t] = f2bf(vv);
    }
  }
}

// ---------------- flash attention, sliding window, GQA ----------------
// grid (T/64, NH, B), 256 thr. HEAVY-FIRST: block bx handles q-tile (31-bx) so the
// 17-key-tile blocks dispatch first and the tail is 1-tile blocks (load balance).
// Block owns queries [q0, q0+64); wave w owns [q0+16w, +16).
// K/V tiles (64x64 bf16) staged cooperatively in double-buffered, XOR-swizzled LDS
// (colbyte ^= (row&7)<<4). Async-stage split: global loads for tile i+1 issue before
// compute of tile i; ds_writes land after compute; one barrier per iteration.
// S^T = K*Q^T via mfma(A=K,B=Q); O^T += V^T * P^T via mfma(A=V^T fragment, B=P^T).
__global__ __launch_bounds__(256, 4) void attn_fwd(
    const unsigned short* __restrict__ Qn, const unsigned short* __restrict__ Kn,
    const unsigned short* __restrict__ Vt, unsigned short* __restrict__ Y,
    const int* __restrict__ wlp) {
  __shared__ unsigned short Kl[2][KVB * 64];   // [s][d], swizzled, 8KB each
  __shared__ unsigned short Vl[2][64 * KVB];   // [d][s], swizzled, 8KB each
  __shared__ unsigned short Pl[4][16 * 64];    // per-wave P tile, 2KB each
  const int b = blockIdx.z, h = blockIdx.y;
  const int kvh = h >> 2;
  const int tid = threadIdx.x;
  const int wid = tid >> 6, lane = tid & 63;
  const int q0 = (gridDim.x - 1 - blockIdx.x) * 64;   // heavy-first
  const int qs = q0 + wid * 16;
  const int r = lane & 15, g = lane >> 4;
  const int wl = *wlp;
  const unsigned short* Qb = Qn + ((size_t)(b * NH + h) * T_ + qs) * HD;
  const unsigned short* Kb = Kn + (size_t)(b * NKV + kvh) * T_ * HD;
  const unsigned short* Vb = Vt + (size_t)(b * NKV + kvh) * HD * T_;
  const bf16x8 qf0 = *reinterpret_cast<const bf16x8*>(Qb + r * HD + g * 8);
  const bf16x8 qf1 = *reinterpret_cast<const bf16x8*>(Qb + r * HD + 32 + g * 8);
  float mrun = -1e30f, lrun = 0.f;
  f32x4 o[4] = {};
  int slo = q0 - wl; if (slo < 0) slo = 0;
  slo &= ~63;
  const int send = q0 + 63;
  // staging map: thread covers rows srow, srow+32 of each 64x128B tile
  const int srow = tid >> 3;            // 0..31
  const int scolb = (tid & 7) * 16;     // byte col 0..112
  const int sdst = srow * 128 + (scolb ^ ((srow & 7) << 4));  // swizzled dest byte
  const unsigned short* Ksrc0 = Kb + (size_t)srow * HD + (scolb >> 1);
  const unsigned short* Ksrc1 = Kb + (size_t)(srow + 32) * HD + (scolb >> 1);
  const unsigned short* Vsrc0 = Vb + (size_t)srow * T_ + (scolb >> 1);
  const unsigned short* Vsrc1 = Vb + (size_t)(srow + 32) * T_ + (scolb >> 1);
  char* Pwb = (char*)Pl[wid];
  const int swz = (r & 7) << 4;
  const int ksw = swz;                  // row&7 == r&7 for all fragment rows
  const int q = qs + r;

  // prologue: stage first tile into buf 0
  bf16x8 ska, skb, sva, svb;
  ska = *reinterpret_cast<const bf16x8*>(Ksrc0 + (size_t)slo * HD);
  skb = *reinterpret_cast<const bf16x8*>(Ksrc1 + (size_t)slo * HD);
  sva = *reinterpret_cast<const bf16x8*>(Vsrc0 + slo);
  svb = *reinterpret_cast<const bf16x8*>(Vsrc1 + slo);
  {
    char* Kd = (char*)Kl[0]; char* Vd = (char*)Vl[0];
    *reinterpret_cast<bf16x8*>(Kd + sdst) = ska;
    *reinterpret_cast<bf16x8*>(Kd + 32 * 128 + sdst) = skb;
    *reinterpret_cast<bf16x8*>(Vd + sdst) = sva;
    *reinterpret_cast<bf16x8*>(Vd + 32 * 128 + sdst) = svb;
  }
  __syncthreads();

  int cur = 0;
  for (int sb = slo; sb <= send; sb += KVB) {
    const bool has_next = (sb + KVB <= send);
    if (has_next) {   // issue next tile's global loads early (latency hides under compute)
      const int nb = sb + KVB;
      ska = *reinterpret_cast<const bf16x8*>(Ksrc0 + (size_t)nb * HD);
      skb = *reinterpret_cast<const bf16x8*>(Ksrc1 + (size_t)nb * HD);
      sva = *reinterpret_cast<const bf16x8*>(Vsrc0 + nb);
      svb = *reinterpret_cast<const bf16x8*>(Vsrc1 + nb);
    }
    if (sb <= qs + 15) {   // wave participates in this key-block
      const char* Kc = (const char*)Kl[cur];
      const char* Vc = (const char*)Vl[cur];
      float sv[16];
#pragma unroll
      for (int sub = 0; sub < 4; ++sub) {
        const int rowb = (sub * 16 + r) * 128;
        bf16x8 kf0 = *reinterpret_cast<const bf16x8*>(Kc + rowb + ((g * 16) ^ ksw));
        bf16x8 kf1 = *reinterpret_cast<const bf16x8*>(Kc + rowb + ((64 + g * 16) ^ ksw));
        f32x4 z = {};
        z = __builtin_amdgcn_mfma_f32_16x16x32_bf16(kf0, qf0, z, 0, 0, 0);
        z = __builtin_amdgcn_mfma_f32_16x16x32_bf16(kf1, qf1, z, 0, 0, 0);
#pragma unroll
        for (int e = 0; e < 4; ++e) sv[sub * 4 + e] = z[e];
      }
      // edge blocks only: causal edge or window edge
      if (sb + 63 > qs || sb < qs + 15 - wl) {
#pragma unroll
        for (int i = 0; i < 16; ++i) {
          const int s_ = sb + (i >> 2) * 16 + g * 4 + (i & 3);
          const bool ok = (unsigned)(q - s_) <= (unsigned)wl;  // 0 <= q-s_ <= wl
          sv[i] = ok ? sv[i] : -__builtin_inff();
        }
      }
      float pm = sv[0];
#pragma unroll
      for (int i = 1; i < 16; ++i) pm = fmaxf(pm, sv[i]);
      pm = fmaxf(pm, __shfl_xor(pm, 16));
      pm = fmaxf(pm, __shfl_xor(pm, 32));
      if (!__all(pm <= mrun + 8.0f)) {          // defer-max (THR=8 in log2 units)
        const float mnew = fmaxf(mrun, pm);
        const float scl = exp2f(mrun - mnew);
        lrun *= scl;
#pragma unroll
        for (int dt = 0; dt < 4; ++dt)
#pragma unroll
          for (int e = 0; e < 4; ++e) o[dt][e] *= scl;
        mrun = mnew;
      }
      float ps = 0.f;
      unsigned short pb[16];
#pragma unroll
      for (int i = 0; i < 16; ++i) {
        const float p = exp2f(sv[i] - mrun);    // scores pre-scaled by log2(e)
        ps += p;
        pb[i] = f2bf(p);
      }
      ps += __shfl_xor(ps, 16);
      ps += __shfl_xor(ps, 32);
      lrun += ps;
      // store P^T tile [q=r][s 0..63] to swizzled per-wave LDS
#pragma unroll
      for (int sub = 0; sub < 4; ++sub) {
        bf16x4 w;
#pragma unroll
        for (int e = 0; e < 4; ++e) w[e] = (short)pb[sub * 4 + e];
        *reinterpret_cast<bf16x4*>(Pwb + ((r * 128 + sub * 32 + g * 8) ^ swz)) = w;
      }
      asm volatile("s_waitcnt lgkmcnt(0)" ::: "memory");
#pragma unroll
      for (int c = 0; c < 2; ++c) {
        const bf16x8 pf = *reinterpret_cast<const bf16x8*>(Pwb + ((r * 128 + c * 64 + g * 16) ^ swz));
#pragma unroll
        for (int dt = 0; dt < 4; ++dt) {
          const int vrow = (dt * 16 + r) * 128;
          const bf16x8 vf = *reinterpret_cast<const bf16x8*>(Vc + vrow + ((c * 64 + g * 16) ^ ksw));
          o[dt] = __builtin_amdgcn_mfma_f32_16x16x32_bf16(vf, pf, o[dt], 0, 0, 0);
        }
      }
    }
    if (has_next) {   // write staged tile to the other buffer (vmcnt wait auto-inserted)
      char* Kd = (char*)Kl[cur ^ 1]; char* Vd = (char*)Vl[cur ^ 1];
      *reinterpret_cast<bf16x8*>(Kd + sdst) = ska;
      *reinterpret_cast<bf16x8*>(Kd + 32 * 128 + sdst) = skb;
      *reinterpret_cast<bf16x8*>(Vd + sdst) = sva;
      *reinterpret_cast<bf16x8*>(Vd + 32 * 128 + sdst) = svb;
    }
    __syncthreads();
    cur ^= 1;
  }
  const float inv = 1.0f / lrun;
  unsigned short* Yb = Y + ((size_t)(b * T_) + qs + r) * (NH * HD) + h * HD;
#pragma unroll
  for (int dt = 0; dt < 4; ++dt)
#pragma unroll
    for (int e = 0; e < 4; ++e)
      Yb[dt * 16 + g * 4 + e] = f2bf(o[dt][e] * inv);
}

extern "C" void kernel_launch(void* const* d_in, const int* in_sizes, int n_in,
                              void* d_out, int out_size, void* d_ws, size_t ws_size,
                              hipStream_t stream) {
  const float* x    = (const float*)d_in[0];
  const float* ve   = (const float*)d_in[1];
  const float* cosb = (const float*)d_in[2];
  const float* sinb = (const float*)d_in[3];
  const float* Wq   = (const float*)d_in[4];
  const float* Wk   = (const float*)d_in[5];
  const float* Wv   = (const float*)d_in[6];
  const float* Wo   = (const float*)d_in[7];
  const float* Wg   = (const float*)d_in[8];
  const int*   wlp  = (const int*)d_in[9];

  char* ws = (char*)d_ws;
  unsigned short* xb    = (unsigned short*)ws; ws += (size_t)4096 * 1024 * 2;
  unsigned short* wqkvb = (unsigned short*)ws; ws += (size_t)1536 * 1024 * 2;
  unsigned short* wob   = (unsigned short*)ws; ws += (size_t)1024 * 1024 * 2;
  float*          qkv   = (float*)ws;          ws += (size_t)4096 * 1536 * 4;
  unsigned short* Qn    = (unsigned short*)ws; ws += (size_t)B_ * NH * T_ * HD * 2;
  unsigned short* Kn    = (unsigned short*)ws; ws += (size_t)B_ * NKV * T_ * HD * 2;
  unsigned short* Vt    = (unsigned short*)ws; ws += (size_t)B_ * NKV * HD * T_ * 2;
  unsigned short* yb    = (unsigned short*)ws; ws += (size_t)4096 * 1024 * 2;

  conv_all<<<dim3(2048), dim3(256), 0, stream>>>(x, Wq, Wk, Wv, Wo, xb, wqkvb, wob);

  gemm_bt<<<dim3(NQKV / BN, 4096 / BM), dim3(256), 0, stream>>>(xb, wqkvb, qkv, 4096, NQKV, 1024);

  postproc<<<dim3(4096), dim3(256), 0, stream>>>(qkv, x, ve, cosb, sinb, Wg, Qn, Kn, Vt);

  attn_fwd<<<dim3(T_ / 64, NH, B_), dim3(256), 0, stream>>>(Qn, Kn, Vt, yb, wlp);

  gemm_bt<<<dim3(1024 / BN, 4096 / BM), dim3(256), 0, stream>>>(yb, wob, (float*)d_out, 4096, 1024, 1024);
}